// Round 1
// baseline (64.951 us; speedup 1.0000x reference)
//
#include <hip/hip_runtime.h>

// PairWiseLoss: per-graph (pos, neg) hinge mean.
//   loss = sum_{g} sum_{i in pos_g, j in neg_g} max(0, 1 - (s_i - s_j))  /  sum_g |pos_g|*|neg_g|
// segment_ids are SORTED -> per-graph ranges found by binary search.

#define NUM_GRAPHS 64
#define BLOCK 256
#define CAP 6144   // per-class LDS capacity; 2*6144*4B = 48KB LDS (<64KB static limit)

__device__ __forceinline__ int lower_bound_i(const int* __restrict__ a, int n, int v) {
    int lo = 0, hi = n;
    while (lo < hi) {
        int mid = (lo + hi) >> 1;
        if (a[mid] < v) lo = mid + 1; else hi = mid;
    }
    return lo;
}

__global__ __launch_bounds__(BLOCK)
void pairwise_per_graph(const float* __restrict__ scores,
                        const int* __restrict__ labels,
                        const int* __restrict__ seg,
                        int n,
                        float* __restrict__ tots,
                        long long* __restrict__ cnts) {
    __shared__ float s_pos[CAP];
    __shared__ float s_neg[CAP];
    __shared__ float sm[BLOCK / 64];
    __shared__ int cp, cn;
    __shared__ unsigned long long sh_cnt;

    const int g   = blockIdx.x;
    const int tid = threadIdx.x;

    // All threads redundantly binary-search (cheap, avoids a broadcast sync).
    const int start = lower_bound_i(seg, n, g);
    const int end   = lower_bound_i(seg, n, g + 1);

    if (tid == 0) { cp = 0; cn = 0; sh_cnt = 0ull; }
    __syncthreads();

    // Compact this graph's scores into LDS by class.
    for (int i = start + tid; i < end; i += BLOCK) {
        float s = scores[i];
        if (labels[i] != 0) {
            int p = atomicAdd(&cp, 1);
            if (p < CAP) s_pos[p] = s;
        } else {
            int p = atomicAdd(&cn, 1);
            if (p < CAP) s_neg[p] = s;
        }
    }
    __syncthreads();

    const int np = cp;
    const int nn = cn;

    float local = 0.0f;
    unsigned long long pairs = 0ull;

    if (np <= CAP && nn <= CAP) {
        // Fast path: LDS-resident double loop. Inner reads are wave-uniform
        // LDS broadcasts (conflict-free).
        for (int p = tid; p < np; p += BLOCK) {
            const float base = 1.0f - s_pos[p];
            for (int j = 0; j < nn; ++j) {
                local += fmaxf(base + s_neg[j], 0.0f);
            }
        }
        if (tid == 0) pairs = (unsigned long long)np * (unsigned long long)nn;
    } else {
        // Fallback (pathological segment larger than CAP): global brute force.
        for (int i = start + tid; i < end; i += BLOCK) {
            if (labels[i] != 0) {
                const float base = 1.0f - scores[i];
                for (int j = start; j < end; ++j) {
                    if (labels[j] == 0) {
                        local += fmaxf(base + scores[j], 0.0f);
                        pairs++;
                    }
                }
            }
        }
    }

    // Count: LDS atomic (fast path adds once from tid 0).
    if (pairs) atomicAdd(&sh_cnt, pairs);

    // Block-reduce the float total: wave shuffle then LDS across 4 waves.
    for (int off = 32; off; off >>= 1) local += __shfl_down(local, off, 64);
    const int wave = tid >> 6, lane = tid & 63;
    if (lane == 0) sm[wave] = local;
    __syncthreads();

    if (tid == 0) {
        float tot = 0.0f;
        #pragma unroll
        for (int w = 0; w < BLOCK / 64; ++w) tot += sm[w];
        tots[g] = tot;
        cnts[g] = (long long)sh_cnt;
    }
}

__global__ __launch_bounds__(64)
void pairwise_finalize(const long long* __restrict__ cnts,
                       const float* __restrict__ tots,
                       float* __restrict__ out) {
    const int t = threadIdx.x;  // 64 threads == 1 wave == NUM_GRAPHS
    float tot = tots[t];
    long long c = cnts[t];
    for (int off = 32; off; off >>= 1) {
        tot += __shfl_down(tot, off, 64);
        c   += __shfl_down(c,   off, 64);
    }
    if (t == 0) {
        out[0] = (c > 0) ? (tot / (float)c) : 0.0f;
    }
}

extern "C" void kernel_launch(void* const* d_in, const int* in_sizes, int n_in,
                              void* d_out, int out_size, void* d_ws, size_t ws_size,
                              hipStream_t stream) {
    const float* scores = (const float*)d_in[0];
    const int*   labels = (const int*)d_in[1];
    const int*   seg    = (const int*)d_in[2];
    float*       out    = (float*)d_out;
    const int n = in_sizes[0];

    // Workspace layout: 64 x int64 counts, then 64 x float totals.
    long long* cnts = (long long*)d_ws;
    float*     tots = (float*)((char*)d_ws + NUM_GRAPHS * sizeof(long long));

    pairwise_per_graph<<<NUM_GRAPHS, BLOCK, 0, stream>>>(scores, labels, seg, n, tots, cnts);
    pairwise_finalize<<<1, 64, 0, stream>>>(cnts, tots, out);
}